// Round 8
// baseline (50180.081 us; speedup 1.0000x reference)
//
#include <hip/hip_runtime.h>
#include <cstdint>
#include <cstddef>

// ---------------- problem constants ----------------
#define T_STEPS 2048
#define NBATCH  64
#define HID     256
#define NGATE   1024            // 4*HID

// recurrent kernel v3: MFMA, 16 batches per block, grid = 4 blocks x 1024 thr.
// Block bg handles batches [bg*16, +16) and ALL 256 units (no exchange).
// 16 waves, 4/SIMD. Wave wv owns units [wv*16, +16) x 4 gates = 4 N-tiles
// x 8 K-tiles = 32 mfma_f32_16x16x32_f16 per step; B-frags (whole w_hh slice)
// live in 128 VGPRs permanently. A = h (M=16 batches) from LDS, 8 ds_read_b128
// per wave per step. C layout puts all 4 gates of (batch,unit) in-lane ->
// lane-local epilogue, no shuffles, ONE barrier per step.
#define HSTR 264                              // h row stride in f16 (pad 256->264)
#define REC_LDS_BYTES (2*16*HSTR*2)           // 2 h buffers = 16896 B

typedef _Float16 f16x8 __attribute__((ext_vector_type(8)));
typedef float    f32x4 __attribute__((ext_vector_type(4)));

__device__ __forceinline__ unsigned short f2h_bits(float f) {
    _Float16 h = (_Float16)f;
    return __builtin_bit_cast(unsigned short, h);
}
__device__ __forceinline__ float h2f_scalar(unsigned short u) {
    return (float)__builtin_bit_cast(_Float16, u);
}

// ---------------- workspace layout (bytes) ----------------
#define OFF_G    ((size_t)0)                    // G swizzled: 2048*4*256*4*4*4 u16 = 268435456
#define OFF_Y0   ((size_t)268435456)            // 2048*64*256 fp16 = 67108864
#define OFF_WF0  ((size_t)335544320)            // 16*4*8*64*8 f16 = 524288 B (w_hh frags)
#define OFF_WF1  ((size_t)336068608)
#define OFF_BS0  ((size_t)336592896)            // 128*1024 fp16 swizzled = 262144 B
#define OFF_BS1  ((size_t)336855040)            // 256*1024 fp16 swizzled = 524288 B
#define WS_NEED  ((size_t)337379328)

// ---------------- weight conversion / swizzle ----------------
// WF fragment layout (B-frag of mfma 16x16x32, same mapping gemm_in uses):
//   WF[(((wv*4 + g)*8 + kt)*64 + lane)*8 + i]
//     = w_hh[k = kt*32 + (lane>>4)*8 + i][col = g*256 + wv*16 + (lane&15)]
__global__ void convert_weights(const float* __restrict__ w_ih0, const float* __restrict__ w_hh0,
                                const float* __restrict__ w_ih1, const float* __restrict__ w_hh1,
                                unsigned short* __restrict__ WF0, unsigned short* __restrict__ WF1,
                                unsigned short* __restrict__ BS0, unsigned short* __restrict__ BS1)
{
    int gid = blockIdx.x * blockDim.x + threadIdx.x;
    int gsz = gridDim.x * blockDim.x;
    // WF: 262144 u16 per layer
    for (int s = gid; s < 262144; s += gsz) {
        int i = s & 7;
        int lane = (s >> 3) & 63;
        int kt = (s >> 9) & 7;
        int g = (s >> 12) & 3;
        int wv = s >> 14;                 // 0..15
        int k = kt * 32 + (lane >> 4) * 8 + i;
        int col = g * 256 + wv * 16 + (lane & 15);
        WF0[s] = f2h_bits(w_hh0[k * 1024 + col]);
        WF1[s] = f2h_bits(w_hh1[k * 1024 + col]);
    }
    // Bswz layer0: K=128 (KB=4): s = ((n16*KB+kb)*64+lane)*8+i
    for (int s = gid; s < 131072; s += gsz) {
        int i = s & 7, lane = (s >> 3) & 63, kb = (s >> 9) & 3, n16 = s >> 11;
        int k = kb * 32 + (lane >> 4) * 8 + i;
        int n = n16 * 16 + (lane & 15);
        BS0[s] = f2h_bits(w_ih0[k * 1024 + n]);
    }
    // Bswz layer1: K=256 (KB=8)
    for (int s = gid; s < 262144; s += gsz) {
        int i = s & 7, lane = (s >> 3) & 63, kb = (s >> 9) & 7, n16 = s >> 12;
        int k = kb * 32 + (lane >> 4) * 8 + i;
        int n = n16 * 16 + (lane & 15);
        BS1[s] = f2h_bits(w_ih1[k * 1024 + n]);
    }
}

// ---------------- input-gate GEMM: G = A @ w_ih + b, stored in lstm-frag order -----
// r = t*64 + b ; layer0: A = x fp32, row (b*2048 + 2047-t), K=128
//                layer1: A = y0 fp16, row ((2047-t)*64 + b), K=256
// G storage (matches lstm_rec v3 lane needs, 16 u16 contiguous per (unit,bq)):
//   idx = ((((t*4 + bg)*256 + u)*4 + bq)*4 + g)*4 + r,  b = bg*16 + bq*4 + r
template <int KB, int LAYER>
__global__ __launch_bounds__(256) void gemm_in(const float* __restrict__ A32,
                                               const unsigned short* __restrict__ A16,
                                               const unsigned short* __restrict__ Bsw,
                                               const float* __restrict__ bias,
                                               unsigned short* __restrict__ Gout)
{
    const int lane = threadIdx.x & 63;
    const int wave = threadIdx.x >> 6;
    const int nblk = blockIdx.x & 15;        // 16 n-blocks of 64 cols
    const int rblk = blockIdx.x >> 4;        // 1024 r-blocks of 128 rows
    const int r0 = rblk * 128 + wave * 32;
    const int quad = lane >> 4, ln = lane & 15;

    f32x4 acc[2][4];
#pragma unroll
    for (int q = 0; q < 4; q++) {
        float bv = bias[(nblk * 4 + q) * 16 + ln];
#pragma unroll
        for (int mt = 0; mt < 2; mt++) {
            acc[mt][q][0] = bv; acc[mt][q][1] = bv; acc[mt][q][2] = bv; acc[mt][q][3] = bv;
        }
    }
    const int ar0 = r0 + ln, ar1 = r0 + 16 + ln;
    size_t aoff0, aoff1;
    if (LAYER == 0) {
        aoff0 = ((size_t)(ar0 & 63) * 2048 + (size_t)(2047 - (ar0 >> 6))) * 128;
        aoff1 = ((size_t)(ar1 & 63) * 2048 + (size_t)(2047 - (ar1 >> 6))) * 128;
    } else {
        aoff0 = ((size_t)(2047 - (ar0 >> 6)) * 64 + (size_t)(ar0 & 63)) * 256;
        aoff1 = ((size_t)(2047 - (ar1 >> 6)) * 64 + (size_t)(ar1 & 63)) * 256;
    }
#pragma unroll
    for (int kb = 0; kb < KB; kb++) {
        const int k0 = kb * 32 + quad * 8;
        f16x8 a0, a1;
        if (LAYER == 0) {
            const float* p0 = A32 + aoff0 + k0;
            const float* p1 = A32 + aoff1 + k0;
            float4 fa = *(const float4*)(p0);
            float4 fb = *(const float4*)(p0 + 4);
            float4 fc = *(const float4*)(p1);
            float4 fd = *(const float4*)(p1 + 4);
            a0[0] = (_Float16)fa.x; a0[1] = (_Float16)fa.y; a0[2] = (_Float16)fa.z; a0[3] = (_Float16)fa.w;
            a0[4] = (_Float16)fb.x; a0[5] = (_Float16)fb.y; a0[6] = (_Float16)fb.z; a0[7] = (_Float16)fb.w;
            a1[0] = (_Float16)fc.x; a1[1] = (_Float16)fc.y; a1[2] = (_Float16)fc.z; a1[3] = (_Float16)fc.w;
            a1[4] = (_Float16)fd.x; a1[5] = (_Float16)fd.y; a1[6] = (_Float16)fd.z; a1[7] = (_Float16)fd.w;
        } else {
            a0 = *(const f16x8*)(A16 + aoff0 + k0);
            a1 = *(const f16x8*)(A16 + aoff1 + k0);
        }
#pragma unroll
        for (int q = 0; q < 4; q++) {
            f16x8 bq = *(const f16x8*)(Bsw + (((size_t)(nblk * 4 + q) * KB + kb) * 64 + lane) * 8);
            acc[0][q] = __builtin_amdgcn_mfma_f32_16x16x32_f16(a0, bq, acc[0][q], 0, 0, 0);
            acc[1][q] = __builtin_amdgcn_mfma_f32_16x16x32_f16(a1, bq, acc[1][q], 0, 0, 0);
        }
    }
    // C/D layout: col = lane&15, row = (lane>>4)*4 + reg.
#pragma unroll
    for (int mt = 0; mt < 2; mt++)
#pragma unroll
        for (int q = 0; q < 4; q++)
#pragma unroll
            for (int rg = 0; rg < 4; rg++) {
                int row = r0 + mt * 16 + quad * 4 + rg;     // t*64 + b
                int col = (nblk * 4 + q) * 16 + ln;          // gate-major col
                int tt = row >> 6, bb = row & 63;
                int u = col & 255, g = col >> 8;
                size_t idx = ((((size_t)tt * 4 + (bb >> 4)) * 256 + u) * 4 + ((bb >> 2) & 3)) * 16
                           + (size_t)g * 4 + (bb & 3);
                Gout[idx] = f2h_bits(acc[mt][q][rg]);
            }
}

// ---------------- persistent recurrent kernel: 1 block per 16-batch group ----------------
// Per step (one barrier):
//   1. prefetch next-step G (2 x b128 per lane)
//   2. deferred global store of h(t-1) (4 stores)
//   3. 8 x ds_read_b128 A-frags from h LDS; 32 MFMA (4 gates x 8 K) into f32x4
//      accumulators initialized with this step's G values
//   4. lane-local epilogue for 4 (batch,unit) pairs; 4 x ds_write h(t+1)
//   5. barrier
template <int LAYER>
__global__ __launch_bounds__(1024, 1) void lstm_rec(const unsigned short* __restrict__ G,
                                                    const unsigned short* __restrict__ WF,
                                                    unsigned short* __restrict__ Y0,
                                                    float* __restrict__ Out)
{
    extern __shared__ char smem[];
    unsigned short* hb0 = (unsigned short*)smem;          // [16][HSTR] f16
    unsigned short* hb1 = hb0 + 16 * HSTR;

    const int bg = blockIdx.x;            // batch group 0..3
    const int tid = threadIdx.x;          // 0..1023
    const int wv = tid >> 6, l = tid & 63;
    const int q = l >> 4, ln = l & 15;
    const int unit = wv * 16 + ln;        // this lane's unit
    const int b0 = bg * 16 + q * 4;       // first of this lane's 4 batches

    // persistent B-fragments: whole w_hh slice for this wave's 16 units x 4 gates
    f16x8 wb[4][8];
#pragma unroll
    for (int g = 0; g < 4; ++g)
#pragma unroll
        for (int kt = 0; kt < 8; ++kt)
            wb[g][kt] = *(const f16x8*)(WF + (((size_t)(wv * 4 + g) * 8 + kt) * 64 + l) * 8);

    for (int i = tid; i < 16 * HSTR; i += 1024) hb0[i] = 0;
    float c0 = 0.f, c1 = 0.f, c2 = 0.f, c3 = 0.f;
    float y0v = 0.f, y1v = 0.f, y2v = 0.f, y3v = 0.f;
    __syncthreads();

    const size_t gstride = (size_t)4 * 256 * 64;          // u16 per t
    const size_t goff = (((size_t)bg * 256 + unit) * 4 + q) * 16;
    const uint4* gp0 = (const uint4*)(G + goff);
    uint4 glo = gp0[0], ghi = gp0[1];                     // t = 0

    for (int t = 0; t < T_STEPS; ++t) {
        // next step's G (full-step latency cover)
        const int tn = (t + 1 < T_STEPS) ? (t + 1) : t;
        const uint4* gpn = (const uint4*)(G + (size_t)tn * gstride + goff);
        uint4 glon = gpn[0], ghin = gpn[1];

        // deferred store of h(t-1): retires during the MFMA phase
        if (t) {
            size_t yb = ((size_t)(t - 1) * 64 + b0) * 256 + unit;
            if (LAYER == 0) {
                Y0[yb]       = f2h_bits(y0v);
                Y0[yb + 256] = f2h_bits(y1v);
                Y0[yb + 512] = f2h_bits(y2v);
                Y0[yb + 768] = f2h_bits(y3v);
            } else {
                Out[yb] = y0v; Out[yb + 256] = y1v; Out[yb + 512] = y2v; Out[yb + 768] = y3v;
            }
        }

        const unsigned short* hc = (t & 1) ? hb1 : hb0;
        // A-frags: lane l -> batch row ln, k = kt*32 + q*8 .. +8
        f16x8 a0 = *(const f16x8*)(hc + ln * HSTR + 0 * 32 + q * 8);
        f16x8 a1 = *(const f16x8*)(hc + ln * HSTR + 1 * 32 + q * 8);
        f16x8 a2 = *(const f16x8*)(hc + ln * HSTR + 2 * 32 + q * 8);
        f16x8 a3 = *(const f16x8*)(hc + ln * HSTR + 3 * 32 + q * 8);
        f16x8 a4 = *(const f16x8*)(hc + ln * HSTR + 4 * 32 + q * 8);
        f16x8 a5 = *(const f16x8*)(hc + ln * HSTR + 5 * 32 + q * 8);
        f16x8 a6 = *(const f16x8*)(hc + ln * HSTR + 6 * 32 + q * 8);
        f16x8 a7 = *(const f16x8*)(hc + ln * HSTR + 7 * 32 + q * 8);

        // accumulators initialized with G (C-in of first MFMA); element r = batch q*4+r
        f32x4 accf, acci, acco, accg;
        accf[0] = h2f_scalar((unsigned short)(glo.x & 0xffff));
        accf[1] = h2f_scalar((unsigned short)(glo.x >> 16));
        accf[2] = h2f_scalar((unsigned short)(glo.y & 0xffff));
        accf[3] = h2f_scalar((unsigned short)(glo.y >> 16));
        acci[0] = h2f_scalar((unsigned short)(glo.z & 0xffff));
        acci[1] = h2f_scalar((unsigned short)(glo.z >> 16));
        acci[2] = h2f_scalar((unsigned short)(glo.w & 0xffff));
        acci[3] = h2f_scalar((unsigned short)(glo.w >> 16));
        acco[0] = h2f_scalar((unsigned short)(ghi.x & 0xffff));
        acco[1] = h2f_scalar((unsigned short)(ghi.x >> 16));
        acco[2] = h2f_scalar((unsigned short)(ghi.y & 0xffff));
        acco[3] = h2f_scalar((unsigned short)(ghi.y >> 16));
        accg[0] = h2f_scalar((unsigned short)(ghi.z & 0xffff));
        accg[1] = h2f_scalar((unsigned short)(ghi.z >> 16));
        accg[2] = h2f_scalar((unsigned short)(ghi.w & 0xffff));
        accg[3] = h2f_scalar((unsigned short)(ghi.w >> 16));

#define MF(A, KT) \
        accf = __builtin_amdgcn_mfma_f32_16x16x32_f16(A, wb[0][KT], accf, 0, 0, 0); \
        acci = __builtin_amdgcn_mfma_f32_16x16x32_f16(A, wb[1][KT], acci, 0, 0, 0); \
        acco = __builtin_amdgcn_mfma_f32_16x16x32_f16(A, wb[2][KT], acco, 0, 0, 0); \
        accg = __builtin_amdgcn_mfma_f32_16x16x32_f16(A, wb[3][KT], accg, 0, 0, 0);
        MF(a0, 0) MF(a1, 1) MF(a2, 2) MF(a3, 3)
        MF(a4, 4) MF(a5, 5) MF(a6, 6) MF(a7, 7)
#undef MF

        // lane-local epilogue x4 batches
#define EPI(R, CS, YV) { \
        float vf = accf[R], vi = acci[R], vo = acco[R], vg = accg[R]; \
        float sf = 1.f / (1.f + __expf(-vf)); \
        float si = 1.f / (1.f + __expf(-vi)); \
        float so = 1.f / (1.f + __expf(-vo)); \
        float tg = 1.f - 2.f / (1.f + __expf(2.f * vg)); \
        CS = sf * CS + si * tg; \
        float tc = 1.f - 2.f / (1.f + __expf(2.f * CS)); \
        YV = so * tc; }
        EPI(0, c0, y0v)
        EPI(1, c1, y1v)
        EPI(2, c2, y2v)
        EPI(3, c3, y3v)
#undef EPI

        unsigned short* hn = (t & 1) ? hb0 : hb1;
        int hb = (q * 4) * HSTR + unit;
        hn[hb]            = f2h_bits(y0v);
        hn[hb + HSTR]     = f2h_bits(y1v);
        hn[hb + 2 * HSTR] = f2h_bits(y2v);
        hn[hb + 3 * HSTR] = f2h_bits(y3v);

        glo = glon; ghi = ghin;
        __syncthreads();
    }
    // final y (t = T-1) + hn/cn
    {
        size_t yb = ((size_t)(T_STEPS - 1) * 64 + b0) * 256 + unit;
        if (LAYER == 0) {
            Y0[yb]       = f2h_bits(y0v);
            Y0[yb + 256] = f2h_bits(y1v);
            Y0[yb + 512] = f2h_bits(y2v);
            Y0[yb + 768] = f2h_bits(y3v);
        } else {
            Out[yb] = y0v; Out[yb + 256] = y1v; Out[yb + 512] = y2v; Out[yb + 768] = y3v;
        }
        size_t hoff = (size_t)33554432 + (size_t)LAYER * 16384 + (size_t)b0 * 256 + unit;
        Out[hoff]       = y0v;            // hn
        Out[hoff + 256] = y1v;
        Out[hoff + 512] = y2v;
        Out[hoff + 768] = y3v;
        size_t coff = hoff + 32768;
        Out[coff]       = c0;             // cn
        Out[coff + 256] = c1;
        Out[coff + 512] = c2;
        Out[coff + 768] = c3;
    }
}

// ---------------- launch ----------------
extern "C" void kernel_launch(void* const* d_in, const int* in_sizes, int n_in,
                              void* d_out, int out_size, void* d_ws, size_t ws_size,
                              hipStream_t stream)
{
    const float* x     = (const float*)d_in[0];
    const float* w_ih0 = (const float*)d_in[1];
    const float* w_hh0 = (const float*)d_in[2];
    const float* b0    = (const float*)d_in[3];
    const float* w_ih1 = (const float*)d_in[4];
    const float* w_hh1 = (const float*)d_in[5];
    const float* b1    = (const float*)d_in[6];
    float* out = (float*)d_out;

    if (ws_size < WS_NEED) return;  // cannot run correctly; fail loudly (output stays poisoned)

    char* ws = (char*)d_ws;
    unsigned short* G   = (unsigned short*)(ws + OFF_G);
    unsigned short* Y0  = (unsigned short*)(ws + OFF_Y0);
    unsigned short* WF0 = (unsigned short*)(ws + OFF_WF0);
    unsigned short* WF1 = (unsigned short*)(ws + OFF_WF1);
    unsigned short* BS0 = (unsigned short*)(ws + OFF_BS0);
    unsigned short* BS1 = (unsigned short*)(ws + OFF_BS1);

    convert_weights<<<1024, 256, 0, stream>>>(w_ih0, w_hh0, w_ih1, w_hh1,
                                              WF0, WF1, BS0, BS1);
    gemm_in<4, 0><<<16384, 256, 0, stream>>>(x, nullptr, BS0, b0, G);
    lstm_rec<0><<<4, 1024, REC_LDS_BYTES, stream>>>(G, WF0, Y0, out);
    gemm_in<8, 1><<<16384, 256, 0, stream>>>(nullptr, Y0, BS1, b1, G);
    lstm_rec<1><<<4, 1024, REC_LDS_BYTES, stream>>>(G, WF1, Y0, out);
}